// Round 4
// baseline (7870.443 us; speedup 1.0000x reference)
//
#include <hip/hip_runtime.h>

#define BSZ 64
#define SLEN 32
#define HID 128
#define VOC 96
#define DEPTH 500
#define TPB 256
#define EPSV 1e-6f

typedef __attribute__((ext_vector_type(2))) float f32x2;

#if defined(__has_builtin)
#if __has_builtin(__builtin_elementwise_fma)
#define VFMA(a, b, c) __builtin_elementwise_fma((a), (b), (c))
#endif
#endif
#ifndef VFMA
__device__ __forceinline__ f32x2 vfma_(f32x2 a, f32x2 b, f32x2 c) {
    f32x2 r; r.x = fmaf(a.x, b.x, c.x); r.y = fmaf(a.y, b.y, c.y); return r;
}
#define VFMA(a, b, c) vfma_((a), (b), (c))
#endif

__device__ __forceinline__ float rsq_fast(float x) {
    float r; asm("v_rsq_f32 %0, %1" : "=v"(r) : "v"(x)); return r;
}

// broadcast one lane's value to all lanes as a wave-uniform scalar (VALU, no LDS)
__device__ __forceinline__ float rdlane(float v, int id) {
    return __int_as_float(__builtin_amdgcn_readlane(__float_as_int(v), id));
}

__device__ __forceinline__ float wave_sum64(float v) {
#pragma unroll
    for (int m = 32; m; m >>= 1) v += __shfl_xor(v, m, 64);
    return v;
}

// swizzled float-index of col j's 4-partial slot base (16B-aligned; XOR spreads
// the 8-lane aliasing across bank groups -> <=2-way conflicts on b32 writes)
__device__ __forceinline__ int pswz(int j) {
    return (4 * j) ^ (((j >> 3) & 7) << 2);
}

__global__ __launch_bounds__(TPB, 1) void rnn_char_lm(
    const int* __restrict__ chars, const float* __restrict__ hidden,
    const float* __restrict__ embed_w, const float* __restrict__ W_g,
    const float* __restrict__ b_g, const float* __restrict__ pre_s,
    const float* __restrict__ post_s, const float* __restrict__ rw_g,
    const float* __restrict__ rb_g, float* __restrict__ out)
{
    __shared__ __align__(16) float pbuf[2][512];   // per-col 4 wave-partials, swizzled
    __shared__ __align__(16) float ssb[2][4];      // per-wave sumsq partials
    __shared__ __align__(16) float hpost[HID];     // post-norm h for readout
    __shared__ float rwT[HID * VOC];               // readout_w transposed [k][v]

    const int b = blockIdx.x;
    const int tid = threadIdx.x;
    const int w = tid >> 6;
    const int lane = tid & 63;

    // one-time: stage readout_w transposed into LDS (round-2 proven)
    for (int e = tid; e < VOC * HID; e += TPB) {
        int v = e >> 7;
        int k = e & (HID - 1);
        rwT[k * VOC + v] = rw_g[e];
    }

    // wave w owns k-quarter [32w, 32w+32). W' = pre_scale[k]*W[k][j] for cols lane, lane+64.
    f32x2 WA[16], WB[16];
#pragma unroll
    for (int q = 0; q < 16; ++q) {
        int k0 = 32 * w + 2 * q;
        f32x2 ta, tb;
        ta.x = pre_s[k0] * W_g[k0 * HID + lane];
        ta.y = pre_s[k0 + 1] * W_g[(k0 + 1) * HID + lane];
        tb.x = pre_s[k0] * W_g[k0 * HID + lane + 64];
        tb.y = pre_s[k0 + 1] * W_g[(k0 + 1) * HID + lane + 64];
        WA[q] = ta; WB[q] = tb;
    }
    const float bA = b_g[lane], bB = b_g[lane + 64];
    const float psA = post_s[lane], psB = post_s[lane + 64];
    const float rbv = (tid < VOC) ? rb_g[tid] : 0.0f;

    // h replicated in every wave: lane holds h[lane], h[lane+64]
    float hA = hidden[b * HID + lane];
    float hB = hidden[b * HID + lane + 64];

    const bool useA = (w < 2);            // quarter source register
    const int kb = (w & 1) * 32;          // quarter's lane-id base within source reg

    // precomputed LDS pointers (both parities)
    const int rot = (w + (lane >> 3)) & 3;
    float* wp0a = &pbuf[0][pswz(lane) + rot];
    float* wp0b = &pbuf[0][pswz(lane + 64) + rot];
    float* wp1a = &pbuf[1][pswz(lane) + rot];
    float* wp1b = &pbuf[1][pswz(lane + 64) + rot];
    const float4* rp0a = (const float4*)&pbuf[0][pswz(lane)];
    const float4* rp0b = (const float4*)&pbuf[0][pswz(lane + 64)];
    const float4* rp1a = (const float4*)&pbuf[1][pswz(lane)];
    const float4* rp1b = (const float4*)&pbuf[1][pswz(lane + 64)];

    __syncthreads();

// one recurrent iteration at compile-time parity P:
// VALU: readlane-broadcast quarter + packed dot/sumsq; LDS: 3 writes + 3 b128 reads.
#define ITER(P)                                                              \
    {                                                                        \
        float hs = useA ? hA : hB;                                           \
        f32x2 aA = {0.f, 0.f}, aB = {0.f, 0.f}, sq = {0.f, 0.f};             \
        _Pragma("unroll")                                                    \
        for (int q = 0; q < 16; ++q) {                                       \
            f32x2 av;                                                        \
            av.x = rdlane(hs, kb + 2 * q);                                   \
            av.y = rdlane(hs, kb + 2 * q + 1);                               \
            aA = VFMA(av, WA[q], aA);                                        \
            aB = VFMA(av, WB[q], aB);                                        \
            sq = VFMA(av, av, sq);                                           \
        }                                                                    \
        *wp##P##a = aA.x + aA.y;                                             \
        *wp##P##b = aB.x + aB.y;                                             \
        ssb[P][w] = sq.x + sq.y;                                             \
        __syncthreads();                                                     \
        float4 g0 = *rp##P##a;                                               \
        float4 g1 = *rp##P##b;                                               \
        float4 sv = *(const float4*)&ssb[P][0];                              \
        float ss = (sv.x + sv.y) + (sv.z + sv.w);                            \
        float rn = rsq_fast(fmaf(ss, 1.0f / HID, EPSV));                     \
        hA += fmaxf(fmaf((g0.x + g0.y) + (g0.z + g0.w), rn, eA), 0.f);       \
        hB += fmaxf(fmaf((g1.x + g1.y) + (g1.z + g1.w), rn, eB), 0.f);       \
    }

    for (int t = 0; t < SLEN; ++t) {
        const int c = chars[b * SLEN + t];
        const float eA = embed_w[c * HID + lane] + bA;
        const float eB = embed_w[c * HID + lane + 64] + bB;

        for (int it = 0; it < DEPTH / 2; ++it) {
            ITER(0)
            ITER(1)
        }

        // ---- end of timestep: post-norm (replaces h), readout ----
        // h replicated -> full sumsq via in-wave reduce, no exchange needed
        float ssq = wave_sum64(hA * hA + hB * hB);
        float rnp = 1.0f / sqrtf(ssq * (1.0f / HID) + EPSV);
        hA = hA * rnp * psA;                  // carry = post-normed h
        hB = hB * rnp * psB;
        if (w == 0) { hpost[lane] = hA; hpost[lane + 64] = hB; }
        __syncthreads();

        if (tid < VOC) {
            float acc0 = 0.0f, acc1 = 0.0f;
            const float4* hp4 = reinterpret_cast<const float4*>(hpost);
#pragma unroll
            for (int k4 = 0; k4 < HID / 4; ++k4) {
                float4 x = hp4[k4];
                acc0 = fmaf(x.x, rwT[(4 * k4 + 0) * VOC + tid], acc0);
                acc1 = fmaf(x.y, rwT[(4 * k4 + 1) * VOC + tid], acc1);
                acc0 = fmaf(x.z, rwT[(4 * k4 + 2) * VOC + tid], acc0);
                acc1 = fmaf(x.w, rwT[(4 * k4 + 3) * VOC + tid], acc1);
            }
            out[(b * SLEN + t) * VOC + tid] = acc0 + acc1 + rbv;
        }
        // next iteration's pbuf writes are disjoint from hpost/rwT; no barrier needed
    }

    if (w == 0) {
        out[BSZ * SLEN * VOC + b * HID + lane] = hA;
        out[BSZ * SLEN * VOC + b * HID + lane + 64] = hB;
    }
}

extern "C" void kernel_launch(void* const* d_in, const int* in_sizes, int n_in,
                              void* d_out, int out_size, void* d_ws, size_t ws_size,
                              hipStream_t stream)
{
    const int* chars      = (const int*)d_in[0];
    const float* hidden   = (const float*)d_in[1];
    const float* embed_w  = (const float*)d_in[2];
    const float* W_g      = (const float*)d_in[3];
    const float* b_g      = (const float*)d_in[4];
    const float* pre_s    = (const float*)d_in[5];
    const float* post_s   = (const float*)d_in[6];
    const float* rw_g     = (const float*)d_in[7];
    const float* rb_g     = (const float*)d_in[8];
    float* out            = (float*)d_out;

    rnn_char_lm<<<dim3(BSZ), dim3(TPB), 0, stream>>>(
        chars, hidden, embed_w, W_g, b_g, pre_s, post_s, rw_g, rb_g, out);
}

// Round 6
// 4480.133 us; speedup vs baseline: 1.7567x; 1.7567x over previous
//
#include <hip/hip_runtime.h>

#define BSZ 64
#define SLEN 32
#define HID 128
#define VOC 96
#define DEPTH 500
#define TPB 256
#define EPSV 1e-6f
#define PAD 20              // floats per 16-float h-chunk (16 data + 4 pad)

typedef __attribute__((ext_vector_type(2))) float f32x2;

#if defined(__has_builtin)
#if __has_builtin(__builtin_elementwise_fma)
#define VFMA(a, b, c) __builtin_elementwise_fma((a), (b), (c))
#endif
#endif
#ifndef VFMA
__device__ __forceinline__ f32x2 vfma_(f32x2 a, f32x2 b, f32x2 c) {
    f32x2 r; r.x = fmaf(a.x, b.x, c.x); r.y = fmaf(a.y, b.y, c.y); return r;
}
#define VFMA(a, b, c) vfma_((a), (b), (c))
#endif

__device__ __forceinline__ float rsq_fast(float x) {
    float r; asm("v_rsq_f32 %0, %1" : "=v"(r) : "v"(x)); return r;
}

// lane-xor butterflies: xor1/xor2 via DPP quad_perm (VALU), xor4 via ds_swizzle.
// CTRL must be a compile-time constant -> template parameter.
template <int CTRL>
__device__ __forceinline__ float qperm(float v) {
    return __int_as_float(__builtin_amdgcn_update_dpp(
        0, __float_as_int(v), CTRL, 0xF, 0xF, true));
}
#define BFLY8(v)                                                               \
    v += qperm<0xB1>(v);  /* xor1 */                                           \
    v += qperm<0x4E>(v);  /* xor2 */                                           \
    v += __int_as_float(__builtin_amdgcn_ds_swizzle(__float_as_int(v), 0x101F)); /* xor4 */

__global__ __launch_bounds__(TPB, 1) void rnn_char_lm(
    const int* __restrict__ chars, const float* __restrict__ hidden,
    const float* __restrict__ embed_w, const float* __restrict__ W_g,
    const float* __restrict__ b_g, const float* __restrict__ pre_s,
    const float* __restrict__ post_s, const float* __restrict__ rw_g,
    const float* __restrict__ rb_g, float* __restrict__ out)
{
    __shared__ __align__(16) float hbuf[2][8 * PAD];  // padded chunked h, dbuf
    __shared__ float rwT[HID * VOC];                  // readout_w transposed [k][v]

    const int b = blockIdx.x;
    const int tid = threadIdx.x;
    const int w = tid >> 6;
    const int lane = tid & 63;
    const int g = lane >> 3;          // col-group: 4 consecutive cols
    const int ch = lane & 7;          // k-chunk: 16 k-values

    const int col0 = 32 * w + 4 * g;  // lane's 4 cols: col0..col0+3
    // padded write index for col0 (chunk layout: h[16C+m] at 20C+m)
    const int widx = PAD * (col0 >> 4) + (col0 & 15);
    const int rbase = PAD * ch;       // lane's read chunk base (float idx)

    // one-time: stage readout_w transposed into LDS (round-2 proven)
    for (int e = tid; e < VOC * HID; e += TPB) {
        int v = e >> 7;
        int k = e & (HID - 1);
        rwT[k * VOC + v] = rw_g[e];
    }

    // one-time: W' = pre_scale[k]*W[k][col0+c], packed over k-pairs. 64 VGPRs.
    f32x2 W2[4][8];
#pragma unroll
    for (int q = 0; q < 8; ++q) {
        int k0 = 16 * ch + 2 * q;
        float p0 = pre_s[k0], p1 = pre_s[k0 + 1];
#pragma unroll
        for (int c = 0; c < 4; ++c) {
            f32x2 t;
            t.x = p0 * W_g[k0 * HID + col0 + c];
            t.y = p1 * W_g[(k0 + 1) * HID + col0 + c];
            W2[c][q] = t;
        }
    }
    const float4 bv  = *(const float4*)&b_g[col0];
    const float4 psv = *(const float4*)&post_s[col0];
    const float rbv = (tid < VOC) ? rb_g[tid] : 0.0f;

    // h for lane's 4 cols (replicated across the 8 ch-lanes of group g)
    float4 hc = *(const float4*)&hidden[b * HID + col0];

    if (ch == 0) *(float4*)&hbuf[0][widx] = hc;   // stage initial h
    __syncthreads();

// one recurrent iteration at compile-time read-parity P (reads P, writes P^1)
#define ITER(P)                                                                \
    {                                                                          \
        const float4* rb = (const float4*)&hbuf[P][rbase];                     \
        float4 x0 = rb[0], x1 = rb[1], x2 = rb[2], x3 = rb[3];                 \
        f32x2 a0 = {0,0}, a1 = {0,0}, a2 = {0,0}, a3 = {0,0}, s = {0,0};       \
        _Pragma("unroll")                                                      \
        for (int q = 0; q < 8; ++q) {                                          \
            const float4 xq = (q < 2) ? x0 : (q < 4) ? x1 : (q < 6) ? x2 : x3; \
            f32x2 hv;                                                          \
            hv.x = (q & 1) ? xq.z : xq.x;                                      \
            hv.y = (q & 1) ? xq.w : xq.y;                                      \
            s  = VFMA(hv, hv, s);                                              \
            a0 = VFMA(hv, W2[0][q], a0);                                       \
            a1 = VFMA(hv, W2[1][q], a1);                                       \
            a2 = VFMA(hv, W2[2][q], a2);                                       \
            a3 = VFMA(hv, W2[3][q], a3);                                       \
        }                                                                      \
        float y0 = a0.x + a0.y, y1 = a1.x + a1.y;                              \
        float y2 = a2.x + a2.y, y3 = a3.x + a3.y;                              \
        float ssl = s.x + s.y;                                                 \
        BFLY8(y0) BFLY8(y1) BFLY8(y2) BFLY8(y3) BFLY8(ssl)                     \
        const float rn = rsq_fast(fmaf(ssl, 1.0f / HID, EPSV));                \
        hc.x += fmaxf(fmaf(y0, rn, ev.x), 0.0f);                               \
        hc.y += fmaxf(fmaf(y1, rn, ev.y), 0.0f);                               \
        hc.z += fmaxf(fmaf(y2, rn, ev.z), 0.0f);                               \
        hc.w += fmaxf(fmaf(y3, rn, ev.w), 0.0f);                               \
        if (ch == 0) *(float4*)&hbuf[P ^ 1][widx] = hc;                        \
        __syncthreads();                                                       \
    }

    for (int t = 0; t < SLEN; ++t) {
        const int c = chars[b * SLEN + t];
        const float4 er = *(const float4*)&embed_w[c * HID + col0];
        float4 ev;
        ev.x = er.x + bv.x; ev.y = er.y + bv.y;
        ev.z = er.z + bv.z; ev.w = er.w + bv.w;

        for (int it = 0; it < DEPTH / 2; ++it) {
            ITER(0)
            ITER(1)
        }
        // after 500 iters, current h sits in hbuf[0]; parity invariant per t.

        // ---- epilogue: post-norm (replaces h) + readout ----
        {
            // sumsq from hbuf[0] via the same chunk reads + butterfly
            const float4* rb = (const float4*)&hbuf[0][rbase];
            float4 x0 = rb[0], x1 = rb[1], x2 = rb[2], x3 = rb[3];
            f32x2 s = {0, 0};
            f32x2 hv;
            hv.x = x0.x; hv.y = x0.y; s = VFMA(hv, hv, s);
            hv.x = x0.z; hv.y = x0.w; s = VFMA(hv, hv, s);
            hv.x = x1.x; hv.y = x1.y; s = VFMA(hv, hv, s);
            hv.x = x1.z; hv.y = x1.w; s = VFMA(hv, hv, s);
            hv.x = x2.x; hv.y = x2.y; s = VFMA(hv, hv, s);
            hv.x = x2.z; hv.y = x2.w; s = VFMA(hv, hv, s);
            hv.x = x3.x; hv.y = x3.y; s = VFMA(hv, hv, s);
            hv.x = x3.z; hv.y = x3.w; s = VFMA(hv, hv, s);
            float ssl = s.x + s.y;
            BFLY8(ssl)
            const float rnp = 1.0f / sqrtf(ssl * (1.0f / HID) + EPSV);
            hc.x *= rnp * psv.x; hc.y *= rnp * psv.y;
            hc.z *= rnp * psv.z; hc.w *= rnp * psv.w;
            __syncthreads();                         // all ss-reads of hbuf[0] done
            if (ch == 0) *(float4*)&hbuf[0][widx] = hc;  // hpost, padded layout
            __syncthreads();                         // visible to readout + next t
        }

        if (tid < VOC) {
            float acc0 = 0.0f, acc1 = 0.0f;
#pragma unroll
            for (int C = 0; C < 8; ++C) {
#pragma unroll
                for (int m4 = 0; m4 < 4; ++m4) {
                    const float4 x = *(const float4*)&hbuf[0][PAD * C + 4 * m4];
                    const int k = 16 * C + 4 * m4;
                    acc0 = fmaf(x.x, rwT[(k + 0) * VOC + tid], acc0);
                    acc1 = fmaf(x.y, rwT[(k + 1) * VOC + tid], acc1);
                    acc0 = fmaf(x.z, rwT[(k + 2) * VOC + tid], acc0);
                    acc1 = fmaf(x.w, rwT[(k + 3) * VOC + tid], acc1);
                }
            }
            out[(b * SLEN + t) * VOC + tid] = acc0 + acc1 + rbv;
        }
        // waves 2-3 run ahead into next t's ITER(0): reads hbuf[0] (no write
        // conflict; first write goes to hbuf[1], gated by its own barrier).
    }

    if (ch == 0)
        *(float4*)&out[BSZ * SLEN * VOC + b * HID + col0] = hc;

#undef ITER
}

extern "C" void kernel_launch(void* const* d_in, const int* in_sizes, int n_in,
                              void* d_out, int out_size, void* d_ws, size_t ws_size,
                              hipStream_t stream)
{
    const int* chars      = (const int*)d_in[0];
    const float* hidden   = (const float*)d_in[1];
    const float* embed_w  = (const float*)d_in[2];
    const float* W_g      = (const float*)d_in[3];
    const float* b_g      = (const float*)d_in[4];
    const float* pre_s    = (const float*)d_in[5];
    const float* post_s   = (const float*)d_in[6];
    const float* rw_g     = (const float*)d_in[7];
    const float* rb_g     = (const float*)d_in[8];
    float* out            = (float*)d_out;

    rnn_char_lm<<<dim3(BSZ), dim3(TPB), 0, stream>>>(
        chars, hidden, embed_w, W_g, b_g, pre_s, post_s, rw_g, rb_g, out);
}